// Round 7
// baseline (782.371 us; speedup 1.0000x reference)
//
#include <hip/hip_runtime.h>
#include <hip/hip_bf16.h>

// ShardAttention R7 (= R6 + ws-size-aware head slabbing restored).
//   ws budget discovery (R6 crash): ws ~= 256 MB -> Hs=8 slabs.
//   xprep: one kernel makes xbT [b][c][t] and xh [b][h][t][64] from x.
//   scores: symmetric tiles (136/head-slab), K=64 single stage, fused exp +
//           row/col sums; mirror tile transposed through LDS (pad 136) ->
//           coalesced 256B row stores.
//   PV: BK=32 m97-structure GEMM, launch_bounds(256,4), XCD swizzle.
//   proj: split-K x4 (K=4096), fp32 partials + reduce.

typedef __hip_bfloat16 bf16;
typedef __bf16 bf16x8 __attribute__((ext_vector_type(8)));
typedef float f32x4 __attribute__((ext_vector_type(4)));

#define B_ 2
#define T_ 2048
#define C_ 1024
#define H_ 16
#define D_ 16384
#define E_ 1024
#define KZ_ 4  // proj split-K chunks

__device__ __forceinline__ void load_lds16(const void* g, void* l) {
  __builtin_amdgcn_global_load_lds(
      (const __attribute__((address_space(1))) void*)g,
      (__attribute__((address_space(3))) void*)l, 16, 0, 0);
}

__device__ __forceinline__ unsigned pack2(float a, float b) {
  union { bf16 h[2]; unsigned u; } p;
  p.h[0] = __float2bfloat16(a);
  p.h[1] = __float2bfloat16(b);
  return p.u;
}

// ---------------- x -> xbT (transpose+cast) and xh (per-head) ----------------
// grid (C/32, T/32, B), block (32,8)
__global__ __launch_bounds__(256) void xprep_kernel(
    const float* __restrict__ x, bf16* __restrict__ xbT,
    bf16* __restrict__ xh) {
  __shared__ float tile[32][33];
  int b = blockIdx.z;
  int c0 = blockIdx.x * 32, r0 = blockIdx.y * 32;
  int tx = threadIdx.x, ty = threadIdx.y;
  const float* in = x + (size_t)b * T_ * C_;
  int c = c0 + tx;
  for (int i = ty; i < 32; i += 8) {
    float v = in[(size_t)(r0 + i) * C_ + c];
    tile[i][tx] = v;
    xh[((size_t)(b * H_ + (c >> 6)) * T_ + r0 + i) * 64 + (c & 63)] =
        __float2bfloat16(v);
  }
  __syncthreads();
  for (int i = ty; i < 32; i += 8)
    xbT[(size_t)b * C_ * T_ + (size_t)(c0 + i) * T_ + r0 + tx] =
        __float2bfloat16(tile[tx][i]);
}

// ---------------- W transpose + cast ----------------
__global__ __launch_bounds__(256) void transpose_cast_kernel(
    const float* __restrict__ in, bf16* __restrict__ out, int rows, int cols) {
  __shared__ float tile[32][33];
  int c0 = blockIdx.x * 32, r0 = blockIdx.y * 32;
  int tx = threadIdx.x, ty = threadIdx.y;
  for (int i = ty; i < 32; i += 8)
    tile[i][tx] = in[(size_t)(r0 + i) * cols + c0 + tx];
  __syncthreads();
  for (int i = ty; i < 32; i += 8)
    out[(size_t)(c0 + i) * rows + r0 + tx] = __float2bfloat16(tile[tx][i]);
}

// ---------------- reduce KZ_ fp32 partials -> out ----------------
__global__ __launch_bounds__(256) void reduce_kernel(
    const float* __restrict__ p, float* __restrict__ out, int n4) {
  int i = blockIdx.x * 256 + threadIdx.x;
  if (i >= n4) return;
  float4 a = ((const float4*)p)[i];
#pragma unroll
  for (int z = 1; z < KZ_; ++z) {
    float4 b = ((const float4*)(p + (size_t)z * n4 * 4))[i];
    a.x += b.x; a.y += b.y; a.z += b.z; a.w += b.w;
  }
  ((float4*)out)[i] = a;
}

// ---------------- scores: symmetric tiles, K=64, exp + sums ----------------
// grid (136, Z). Mirror tile transposed through padded LDS -> coalesced rows.
__global__ __launch_bounds__(256) void scores_kernel(
    const bf16* __restrict__ xh,  // [Z][T][64] (slab base)
    bf16* __restrict__ P,         // [Z][T][T]
    float* __restrict__ lsum) {   // [Z][T], pre-zeroed
  int L = blockIdx.x;
  int z = blockIdx.y;
  int ti = 0, rem = L;
  while (rem >= H_ - ti) { rem -= H_ - ti; ++ti; }
  int tj = ti + rem;  // ti <= tj

  const bf16* A = xh + (size_t)z * T_ * 64;
  bf16* Pz = P + (size_t)z * T_ * T_;
  size_t row0 = (size_t)ti * 128, col0 = (size_t)tj * 128;

  // smem: staging (2x 128x64 = 16K elems) overlaid with mirror buf 128x136
  __shared__ __align__(16) bf16 smem[128 * 136];
  bf16* lds_a = smem;
  bf16* lds_b = smem + 128 * 64;
  int t = threadIdx.x;

  const bf16* ga = A + (row0 + (t >> 3)) * 64 + (t & 7) * 8;
  const bf16* gb = A + (col0 + (t >> 3)) * 64 + (t & 7) * 8;
#pragma unroll
  for (int q = 0; q < 4; ++q) {
    load_lds16(ga + q * 32 * 64, lds_a + t * 8 + q * 2048);
    load_lds16(gb + q * 32 * 64, lds_b + t * 8 + q * 2048);
  }
  __syncthreads();

  int lane = t & 63, w = t >> 6;
  int wm = (w & 1) * 64, wn = (w >> 1) * 64;
  int lr = lane & 15, lq = lane >> 4;
  const int a_off = (wm + lr) * 64 + lq * 8;
  const int b_off = (wn + lr) * 64 + lq * 8;

  f32x4 acc[4][4] = {};
#pragma unroll
  for (int kh = 0; kh < 2; ++kh) {
    bf16x8 af[4], bfr[4];
#pragma unroll
    for (int i = 0; i < 4; ++i)
      af[i] = *(const bf16x8*)&lds_a[a_off + kh * 32 + i * 16 * 64];
#pragma unroll
    for (int j = 0; j < 4; ++j)
      bfr[j] = *(const bf16x8*)&lds_b[b_off + kh * 32 + j * 16 * 64];
#pragma unroll
    for (int i = 0; i < 4; ++i)
#pragma unroll
      for (int j = 0; j < 4; ++j)
        acc[i][j] = __builtin_amdgcn_mfma_f32_16x16x32_bf16(af[i], bfr[j],
                                                            acc[i][j], 0, 0, 0);
  }
  __syncthreads();  // staging LDS now dead; reuse as mirror buffer

  float rs[4][4];
  float cs[4];
#pragma unroll
  for (int i2 = 0; i2 < 4; ++i2)
#pragma unroll
    for (int reg = 0; reg < 4; ++reg) rs[i2][reg] = 0.f;
#pragma unroll
  for (int j2 = 0; j2 < 4; ++j2) cs[j2] = 0.f;

#pragma unroll
  for (int i2 = 0; i2 < 4; ++i2) {
    int rbl = wm + i2 * 16 + lq * 4;  // tile-local row base
    size_t rb = row0 + rbl;
#pragma unroll
    for (int j2 = 0; j2 < 4; ++j2) {
      int cl = wn + j2 * 16 + lr;  // tile-local col
      size_t c = col0 + cl;
      float e[4];
#pragma unroll
      for (int reg = 0; reg < 4; ++reg) {
        e[reg] = __expf(acc[i2][j2][reg] * 0.125f);
        rs[i2][reg] += e[reg];
        cs[j2] += e[reg];
        float nb = __shfl_xor(e[reg], 1);
        if ((lr & 1) == 0)
          *(unsigned*)&Pz[(rb + reg) * T_ + c] = pack2(e[reg], nb);
      }
      if (ti != tj) {  // stage mirror values transposed: smem[cl][rbl..+3]
        uint2 mv;
        mv.x = pack2(e[0], e[1]);
        mv.y = pack2(e[2], e[3]);
        *(uint2*)&smem[cl * 136 + rbl] = mv;
      }
    }
  }

  // row sums -> atomics
#pragma unroll
  for (int i2 = 0; i2 < 4; ++i2)
#pragma unroll
    for (int reg = 0; reg < 4; ++reg) {
#pragma unroll
      for (int off = 1; off < 16; off <<= 1)
        rs[i2][reg] += __shfl_xor(rs[i2][reg], off);
    }
  if (lr == 0) {
#pragma unroll
    for (int i2 = 0; i2 < 4; ++i2) {
      size_t rb = row0 + wm + i2 * 16 + lq * 4;
#pragma unroll
      for (int reg = 0; reg < 4; ++reg)
        atomicAdd(&lsum[(size_t)z * T_ + rb + reg], rs[i2][reg]);
    }
  }
  if (ti != tj) {
    // col sums (mirror rows)
#pragma unroll
    for (int j2 = 0; j2 < 4; ++j2) {
      cs[j2] += __shfl_xor(cs[j2], 16);
      cs[j2] += __shfl_xor(cs[j2], 32);
    }
    if (lq == 0) {
#pragma unroll
      for (int j2 = 0; j2 < 4; ++j2) {
        size_t c = col0 + wn + j2 * 16 + lr;
        atomicAdd(&lsum[(size_t)z * T_ + c], cs[j2]);
      }
    }
    // coalesced mirror writeout: 16 rows/pass x 8 passes, 256B per row
    __syncthreads();
#pragma unroll
    for (int p = 0; p < 8; ++p) {
      int r = p * 16 + (t >> 4);
      int ch = t & 15;
      bf16x8 v = *(const bf16x8*)&smem[r * 136 + ch * 8];
      *(bf16x8*)&Pz[(col0 + r) * T_ + row0 + ch * 8] = v;
    }
  }
}

// ---------------- bf16 NT GEMM, 128x128 tile, BK=32, MFMA ----------------
// z decomposed as zo=bz>>4, zi=bz&15; base offsets = zo*X_zo + zi*X_zi.
// MODE 0: store f32   MODE 3: pack-store bf16(v / lsum[bz*T_ + r])
template <int MODE, int SWZ>
__global__ __launch_bounds__(256, 4) void gemm_bt_kernel(
    const bf16* __restrict__ A, long long a_zo, long long a_zi, int lda,
    const bf16* __restrict__ BT, long long b_zo, long long b_zi, int ldb,
    void* __restrict__ Cout, int ldc, long long c_zo, long long c_zi,
    const float* __restrict__ lsum, int K) {
  __shared__ bf16 lds_a[128 * 32];
  __shared__ bf16 lds_b[128 * 32];
  int t = threadIdx.x;

  int bx = blockIdx.x, by = blockIdx.y, bz = blockIdx.z;
  if (SWZ) {
    int gx = gridDim.x, gy = gridDim.y, gz = gridDim.z;
    int S = gy * gz, nb = gx * S;
    if (((S & 7) == 0) && ((nb & 7) == 0)) {
      int L = bx + gx * (by + gy * bz);
      int xcd = L & 7, m = L >> 3, spx = S >> 3;
      int col = m % gx, sl = m / gx;
      int strip = xcd * spx + sl;
      bx = col; by = strip % gy; bz = strip / gy;
    }
  }
  int zo = bz >> 4, zi = bz & 15;

  const bf16* Ab = A + (size_t)zo * a_zo + (size_t)zi * a_zi;
  const bf16* Bb = BT + (size_t)zo * b_zo + (size_t)zi * b_zi;
  size_t row0 = (size_t)by * 128;
  size_t col0 = (size_t)bx * 128;

  const bf16* ga = Ab + (row0 + (t >> 2)) * (size_t)lda + (t & 3) * 8;
  const bf16* gb = Bb + (col0 + (t >> 2)) * (size_t)ldb + (t & 3) * 8;
  bf16* la = lds_a + t * 8;
  bf16* lb = lds_b + t * 8;

  f32x4 acc[4][4] = {};
  int lane = t & 63;
  int w = t >> 6;
  int wm = (w & 1) * 64, wn = (w >> 1) * 64;
  int lr = lane & 15, lq = lane >> 4;
  const int a_off0 = (wm + lr) * 32 + lq * 8;
  const int b_off0 = (wn + lr) * 32 + lq * 8;

  for (int k0 = 0; k0 < K; k0 += 32) {
    load_lds16(ga, la);
    load_lds16(ga + 64 * (size_t)lda, la + 64 * 32);
    load_lds16(gb, lb);
    load_lds16(gb + 64 * (size_t)ldb, lb + 64 * 32);
    ga += 32;
    gb += 32;
    __syncthreads();

    bf16x8 af[4], bfr[4];
#pragma unroll
    for (int i = 0; i < 4; ++i)
      af[i] = *(const bf16x8*)&lds_a[a_off0 + i * 16 * 32];
#pragma unroll
    for (int j = 0; j < 4; ++j)
      bfr[j] = *(const bf16x8*)&lds_b[b_off0 + j * 16 * 32];
#pragma unroll
    for (int i = 0; i < 4; ++i)
#pragma unroll
      for (int j = 0; j < 4; ++j)
        acc[i][j] = __builtin_amdgcn_mfma_f32_16x16x32_bf16(af[i], bfr[j],
                                                            acc[i][j], 0, 0, 0);
    __syncthreads();
  }

  // epilogue: C/D layout col=lane&15, row=(lane>>4)*4+reg (m89/m91 verified)
  size_t cbase = (size_t)zo * c_zo + (size_t)zi * c_zi + col0;
#pragma unroll
  for (int i = 0; i < 4; ++i) {
    size_t r = row0 + wm + i * 16 + lq * 4;
    float4 inv4 = make_float4(1.f, 1.f, 1.f, 1.f);
    if (MODE == 3) {
      float4 lv = *(const float4*)&lsum[(size_t)bz * T_ + r];
      inv4 = make_float4(1.f / lv.x, 1.f / lv.y, 1.f / lv.z, 1.f / lv.w);
    }
#pragma unroll
    for (int j = 0; j < 4; ++j) {
      size_t c = cbase + wn + j * 16 + lr;
#pragma unroll
      for (int reg = 0; reg < 4; ++reg) {
        float v = acc[i][j][reg];
        size_t idx = (r + reg) * (size_t)ldc + c;
        if (MODE == 0) {
          ((float*)Cout)[idx] = v;
        } else {
          float iv = reg == 0 ? inv4.x : reg == 1 ? inv4.y : reg == 2 ? inv4.z
                                                                      : inv4.w;
          v *= iv;
          float nb = __shfl_xor(v, 1);
          if ((lr & 1) == 0) *(unsigned*)&((bf16*)Cout)[idx] = pack2(v, nb);
        }
      }
    }
  }
}

extern "C" void kernel_launch(void* const* d_in, const int* in_sizes, int n_in,
                              void* d_out, int out_size, void* d_ws,
                              size_t ws_size, hipStream_t stream) {
  const float* x = (const float*)d_in[0];    // [B, T, C] fp32
  const float* wgt = (const float*)d_in[1];  // [D, E] fp32
  float* out = (float*)d_out;                // [B, T, E] fp32

  // ws layout
  bf16* xbT = (bf16*)d_ws;                        // [B][C][T]    8 MB
  bf16* wbT = xbT + (size_t)B_ * C_ * T_;         // [E][D]      32 MB
  bf16* xh = wbT + (size_t)E_ * D_;               // [B][H][T][64] 8 MB
  bf16* Obuf = xh + (size_t)B_ * H_ * T_ * 64;    // [B*T][D]   128 MB
  float* lsum = (float*)(Obuf + (size_t)B_ * T_ * D_);  // [32][T] 256 KB
  bf16* P = (bf16*)(lsum + (size_t)32 * T_);      // [Hs][T][T] slab
  float* partials = (float*)P;                    // proj partials (67 MB)

  size_t fixed = ((size_t)B_ * C_ * T_ + (size_t)E_ * D_ +
                  (size_t)B_ * H_ * T_ * 64 + (size_t)B_ * T_ * D_) * 2 +
                 (size_t)32 * T_ * 4;
  // head-slab size so the P slab fits in the remaining workspace
  int Hs = 16;
  while (Hs > 1 && fixed + (size_t)Hs * T_ * T_ * 2 > ws_size) Hs >>= 1;
  bool bigP = fixed + (size_t)32 * T_ * T_ * 2 <= ws_size;  // both batches

  xprep_kernel<<<dim3(C_ / 32, T_ / 32, B_), dim3(32, 8), 0, stream>>>(x, xbT,
                                                                       xh);
  transpose_cast_kernel<<<dim3(E_ / 32, D_ / 32, 1), dim3(32, 8), 0, stream>>>(
      wgt, wbT, D_, E_);

  if (bigP) {
    // both batches in one scores dispatch + one PV dispatch (z = b*16+h)
    hipMemsetAsync(lsum, 0, (size_t)32 * T_ * sizeof(float), stream);
    scores_kernel<<<dim3(136, 32), 256, 0, stream>>>(xh, P, lsum);
    gemm_bt_kernel<3, 1><<<dim3(C_ / 128, T_ / 128, 32), 256, 0, stream>>>(
        P, 16LL * T_ * T_, (long long)T_ * T_, T_,
        xbT, (long long)C_ * T_, 0LL, T_,
        (void*)Obuf, D_, (long long)T_ * D_, (long long)C_, lsum, T_);
  } else {
    for (int b = 0; b < B_; ++b) {
      for (int h0 = 0; h0 < H_; h0 += Hs) {
        const bf16* xhs = xh + (size_t)(b * H_ + h0) * T_ * 64;
        hipMemsetAsync(lsum, 0, (size_t)Hs * T_ * sizeof(float), stream);
        scores_kernel<<<dim3(136, Hs), 256, 0, stream>>>(xhs, P, lsum);
        gemm_bt_kernel<3, 1><<<dim3(C_ / 128, T_ / 128, Hs), 256, 0, stream>>>(
            P, 0LL, (long long)T_ * T_, T_,
            xbT + (size_t)b * C_ * T_, 0LL, 0LL, T_,
            (void*)(Obuf + (size_t)b * T_ * D_ + (size_t)h0 * C_), D_, 0LL,
            (long long)C_, lsum, T_);
      }
    }
  }
  // proj: partials[z] = O[:, z*4096:(z+1)*4096] @ W[z*4096:(z+1)*4096, :]
  gemm_bt_kernel<0, 1><<<dim3(E_ / 128, (B_ * T_) / 128, KZ_), 256, 0,
                         stream>>>(Obuf, 0LL, (long long)(D_ / KZ_), D_,
                                   wbT, 0LL, (long long)(D_ / KZ_), D_,
                                   (void*)partials, E_, 0LL,
                                   (long long)B_ * T_ * E_, nullptr, D_ / KZ_);
  reduce_kernel<<<(B_ * T_ * E_ / 4 + 255) / 256, 256, 0, stream>>>(
      partials, out, B_ * T_ * E_ / 4);
}

// Round 8
// 765.409 us; speedup vs baseline: 1.0222x; 1.0222x over previous
//
#include <hip/hip_runtime.h>
#include <hip/hip_bf16.h>

// ShardAttention R8 (= R7 with the scores-mirror regression reverted):
//   xprep: one kernel makes xbT [b][c][t] and xh [b][h][t][64] from x.
//   scores: symmetric tiles (136/head-slab), K=64 single stage, fused exp +
//           row/col sums; mirror via direct packed uint2 stores (R5 style —
//           per mirror row a wave writes a contiguous 128B segment; L2
//           write-combines. The R7 LDS-transpose path was a net loss).
//   PV: BK=32 m97-structure GEMM, launch_bounds(256,4), XCD swizzle.
//   proj: split-K x4 (K=4096), fp32 partials + reduce.
//   lsum: single upfront memset, absolute head-instance indexing.

typedef __hip_bfloat16 bf16;
typedef __bf16 bf16x8 __attribute__((ext_vector_type(8)));
typedef float f32x4 __attribute__((ext_vector_type(4)));

#define B_ 2
#define T_ 2048
#define C_ 1024
#define H_ 16
#define D_ 16384
#define E_ 1024
#define KZ_ 4  // proj split-K chunks

__device__ __forceinline__ void load_lds16(const void* g, void* l) {
  __builtin_amdgcn_global_load_lds(
      (const __attribute__((address_space(1))) void*)g,
      (__attribute__((address_space(3))) void*)l, 16, 0, 0);
}

__device__ __forceinline__ unsigned pack2(float a, float b) {
  union { bf16 h[2]; unsigned u; } p;
  p.h[0] = __float2bfloat16(a);
  p.h[1] = __float2bfloat16(b);
  return p.u;
}

// ---------------- x -> xbT (transpose+cast) and xh (per-head) ----------------
// grid (C/32, T/32, B), block (32,8)
__global__ __launch_bounds__(256) void xprep_kernel(
    const float* __restrict__ x, bf16* __restrict__ xbT,
    bf16* __restrict__ xh) {
  __shared__ float tile[32][33];
  int b = blockIdx.z;
  int c0 = blockIdx.x * 32, r0 = blockIdx.y * 32;
  int tx = threadIdx.x, ty = threadIdx.y;
  const float* in = x + (size_t)b * T_ * C_;
  int c = c0 + tx;
  for (int i = ty; i < 32; i += 8) {
    float v = in[(size_t)(r0 + i) * C_ + c];
    tile[i][tx] = v;
    xh[((size_t)(b * H_ + (c >> 6)) * T_ + r0 + i) * 64 + (c & 63)] =
        __float2bfloat16(v);
  }
  __syncthreads();
  for (int i = ty; i < 32; i += 8)
    xbT[(size_t)b * C_ * T_ + (size_t)(c0 + i) * T_ + r0 + tx] =
        __float2bfloat16(tile[tx][i]);
}

// ---------------- W transpose + cast ----------------
__global__ __launch_bounds__(256) void transpose_cast_kernel(
    const float* __restrict__ in, bf16* __restrict__ out, int rows, int cols) {
  __shared__ float tile[32][33];
  int c0 = blockIdx.x * 32, r0 = blockIdx.y * 32;
  int tx = threadIdx.x, ty = threadIdx.y;
  for (int i = ty; i < 32; i += 8)
    tile[i][tx] = in[(size_t)(r0 + i) * cols + c0 + tx];
  __syncthreads();
  for (int i = ty; i < 32; i += 8)
    out[(size_t)(c0 + i) * rows + r0 + tx] = __float2bfloat16(tile[tx][i]);
}

// ---------------- reduce KZ_ fp32 partials -> out ----------------
__global__ __launch_bounds__(256) void reduce_kernel(
    const float* __restrict__ p, float* __restrict__ out, int n4) {
  int i = blockIdx.x * 256 + threadIdx.x;
  if (i >= n4) return;
  float4 a = ((const float4*)p)[i];
#pragma unroll
  for (int z = 1; z < KZ_; ++z) {
    float4 b = ((const float4*)(p + (size_t)z * n4 * 4))[i];
    a.x += b.x; a.y += b.y; a.z += b.z; a.w += b.w;
  }
  ((float4*)out)[i] = a;
}

// ---------------- scores: symmetric tiles, K=64, exp + sums ----------------
// grid (136, Z). Direct + mirrored packed stores, fused row/col sums.
__global__ __launch_bounds__(256) void scores_kernel(
    const bf16* __restrict__ xh,  // [Z][T][64] (slab base)
    bf16* __restrict__ P,         // [Z][T][T]
    float* __restrict__ lsum) {   // [Z][T], pre-zeroed
  int L = blockIdx.x;
  int z = blockIdx.y;
  int ti = 0, rem = L;
  while (rem >= H_ - ti) { rem -= H_ - ti; ++ti; }
  int tj = ti + rem;  // ti <= tj

  const bf16* A = xh + (size_t)z * T_ * 64;
  bf16* Pz = P + (size_t)z * T_ * T_;
  size_t row0 = (size_t)ti * 128, col0 = (size_t)tj * 128;

  __shared__ __align__(16) bf16 lds_a[128 * 64];
  __shared__ __align__(16) bf16 lds_b[128 * 64];
  int t = threadIdx.x;

  const bf16* ga = A + (row0 + (t >> 3)) * 64 + (t & 7) * 8;
  const bf16* gb = A + (col0 + (t >> 3)) * 64 + (t & 7) * 8;
#pragma unroll
  for (int q = 0; q < 4; ++q) {
    load_lds16(ga + q * 32 * 64, lds_a + t * 8 + q * 2048);
    load_lds16(gb + q * 32 * 64, lds_b + t * 8 + q * 2048);
  }
  __syncthreads();

  int lane = t & 63, w = t >> 6;
  int wm = (w & 1) * 64, wn = (w >> 1) * 64;
  int lr = lane & 15, lq = lane >> 4;
  const int a_off = (wm + lr) * 64 + lq * 8;
  const int b_off = (wn + lr) * 64 + lq * 8;

  f32x4 acc[4][4] = {};
#pragma unroll
  for (int kh = 0; kh < 2; ++kh) {
    bf16x8 af[4], bfr[4];
#pragma unroll
    for (int i = 0; i < 4; ++i)
      af[i] = *(const bf16x8*)&lds_a[a_off + kh * 32 + i * 16 * 64];
#pragma unroll
    for (int j = 0; j < 4; ++j)
      bfr[j] = *(const bf16x8*)&lds_b[b_off + kh * 32 + j * 16 * 64];
#pragma unroll
    for (int i = 0; i < 4; ++i)
#pragma unroll
      for (int j = 0; j < 4; ++j)
        acc[i][j] = __builtin_amdgcn_mfma_f32_16x16x32_bf16(af[i], bfr[j],
                                                            acc[i][j], 0, 0, 0);
  }

  float rs[4][4];
  float cs[4];
#pragma unroll
  for (int i2 = 0; i2 < 4; ++i2)
#pragma unroll
    for (int reg = 0; reg < 4; ++reg) rs[i2][reg] = 0.f;
#pragma unroll
  for (int j2 = 0; j2 < 4; ++j2) cs[j2] = 0.f;

#pragma unroll
  for (int i2 = 0; i2 < 4; ++i2) {
    size_t rb = row0 + wm + i2 * 16 + lq * 4;
#pragma unroll
    for (int j2 = 0; j2 < 4; ++j2) {
      size_t c = col0 + wn + j2 * 16 + lr;
      float e[4];
#pragma unroll
      for (int reg = 0; reg < 4; ++reg) {
        e[reg] = __expf(acc[i2][j2][reg] * 0.125f);
        rs[i2][reg] += e[reg];
        cs[j2] += e[reg];
        float nb = __shfl_xor(e[reg], 1);
        if ((lr & 1) == 0)
          *(unsigned*)&Pz[(rb + reg) * T_ + c] = pack2(e[reg], nb);
      }
      if (ti != tj) {  // mirror: P[c][rb..rb+3], packed 8B
        uint2 mv;
        mv.x = pack2(e[0], e[1]);
        mv.y = pack2(e[2], e[3]);
        *(uint2*)&Pz[c * T_ + rb] = mv;
      }
    }
  }

  // row sums -> atomics
#pragma unroll
  for (int i2 = 0; i2 < 4; ++i2)
#pragma unroll
    for (int reg = 0; reg < 4; ++reg) {
#pragma unroll
      for (int off = 1; off < 16; off <<= 1)
        rs[i2][reg] += __shfl_xor(rs[i2][reg], off);
    }
  if (lr == 0) {
#pragma unroll
    for (int i2 = 0; i2 < 4; ++i2) {
      size_t rb = row0 + wm + i2 * 16 + lq * 4;
#pragma unroll
      for (int reg = 0; reg < 4; ++reg)
        atomicAdd(&lsum[(size_t)z * T_ + rb + reg], rs[i2][reg]);
    }
  }
  if (ti != tj) {  // col sums (mirror rows)
#pragma unroll
    for (int j2 = 0; j2 < 4; ++j2) {
      cs[j2] += __shfl_xor(cs[j2], 16);
      cs[j2] += __shfl_xor(cs[j2], 32);
    }
    if (lq == 0) {
#pragma unroll
      for (int j2 = 0; j2 < 4; ++j2) {
        size_t c = col0 + wn + j2 * 16 + lr;
        atomicAdd(&lsum[(size_t)z * T_ + c], cs[j2]);
      }
    }
  }
}

// ---------------- bf16 NT GEMM, 128x128 tile, BK=32, MFMA ----------------
// z decomposed as zo=bz>>4, zi=bz&15; base offsets = zo*X_zo + zi*X_zi.
// MODE 0: store f32   MODE 3: pack-store bf16(v / lsum[bz*T_ + r])
template <int MODE, int SWZ>
__global__ __launch_bounds__(256, 4) void gemm_bt_kernel(
    const bf16* __restrict__ A, long long a_zo, long long a_zi, int lda,
    const bf16* __restrict__ BT, long long b_zo, long long b_zi, int ldb,
    void* __restrict__ Cout, int ldc, long long c_zo, long long c_zi,
    const float* __restrict__ lsum, int K) {
  __shared__ bf16 lds_a[128 * 32];
  __shared__ bf16 lds_b[128 * 32];
  int t = threadIdx.x;

  int bx = blockIdx.x, by = blockIdx.y, bz = blockIdx.z;
  if (SWZ) {
    int gx = gridDim.x, gy = gridDim.y, gz = gridDim.z;
    int S = gy * gz, nb = gx * S;
    if (((S & 7) == 0) && ((nb & 7) == 0)) {
      int L = bx + gx * (by + gy * bz);
      int xcd = L & 7, m = L >> 3, spx = S >> 3;
      int col = m % gx, sl = m / gx;
      int strip = xcd * spx + sl;
      bx = col; by = strip % gy; bz = strip / gy;
    }
  }
  int zo = bz >> 4, zi = bz & 15;

  const bf16* Ab = A + (size_t)zo * a_zo + (size_t)zi * a_zi;
  const bf16* Bb = BT + (size_t)zo * b_zo + (size_t)zi * b_zi;
  size_t row0 = (size_t)by * 128;
  size_t col0 = (size_t)bx * 128;

  const bf16* ga = Ab + (row0 + (t >> 2)) * (size_t)lda + (t & 3) * 8;
  const bf16* gb = Bb + (col0 + (t >> 2)) * (size_t)ldb + (t & 3) * 8;
  bf16* la = lds_a + t * 8;
  bf16* lb = lds_b + t * 8;

  f32x4 acc[4][4] = {};
  int lane = t & 63;
  int w = t >> 6;
  int wm = (w & 1) * 64, wn = (w >> 1) * 64;
  int lr = lane & 15, lq = lane >> 4;
  const int a_off0 = (wm + lr) * 32 + lq * 8;
  const int b_off0 = (wn + lr) * 32 + lq * 8;

  for (int k0 = 0; k0 < K; k0 += 32) {
    load_lds16(ga, la);
    load_lds16(ga + 64 * (size_t)lda, la + 64 * 32);
    load_lds16(gb, lb);
    load_lds16(gb + 64 * (size_t)ldb, lb + 64 * 32);
    ga += 32;
    gb += 32;
    __syncthreads();

    bf16x8 af[4], bfr[4];
#pragma unroll
    for (int i = 0; i < 4; ++i)
      af[i] = *(const bf16x8*)&lds_a[a_off0 + i * 16 * 32];
#pragma unroll
    for (int j = 0; j < 4; ++j)
      bfr[j] = *(const bf16x8*)&lds_b[b_off0 + j * 16 * 32];
#pragma unroll
    for (int i = 0; i < 4; ++i)
#pragma unroll
      for (int j = 0; j < 4; ++j)
        acc[i][j] = __builtin_amdgcn_mfma_f32_16x16x32_bf16(af[i], bfr[j],
                                                            acc[i][j], 0, 0, 0);
    __syncthreads();
  }

  // epilogue: C/D layout col=lane&15, row=(lane>>4)*4+reg (m89/m91 verified)
  size_t cbase = (size_t)zo * c_zo + (size_t)zi * c_zi + col0;
#pragma unroll
  for (int i = 0; i < 4; ++i) {
    size_t r = row0 + wm + i * 16 + lq * 4;
    float4 inv4 = make_float4(1.f, 1.f, 1.f, 1.f);
    if (MODE == 3) {
      float4 lv = *(const float4*)&lsum[(size_t)bz * T_ + r];
      inv4 = make_float4(1.f / lv.x, 1.f / lv.y, 1.f / lv.z, 1.f / lv.w);
    }
#pragma unroll
    for (int j = 0; j < 4; ++j) {
      size_t c = cbase + wn + j * 16 + lr;
#pragma unroll
      for (int reg = 0; reg < 4; ++reg) {
        float v = acc[i][j][reg];
        size_t idx = (r + reg) * (size_t)ldc + c;
        if (MODE == 0) {
          ((float*)Cout)[idx] = v;
        } else {
          float iv = reg == 0 ? inv4.x : reg == 1 ? inv4.y : reg == 2 ? inv4.z
                                                                      : inv4.w;
          v *= iv;
          float nb = __shfl_xor(v, 1);
          if ((lr & 1) == 0) *(unsigned*)&((bf16*)Cout)[idx] = pack2(v, nb);
        }
      }
    }
  }
}

extern "C" void kernel_launch(void* const* d_in, const int* in_sizes, int n_in,
                              void* d_out, int out_size, void* d_ws,
                              size_t ws_size, hipStream_t stream) {
  const float* x = (const float*)d_in[0];    // [B, T, C] fp32
  const float* wgt = (const float*)d_in[1];  // [D, E] fp32
  float* out = (float*)d_out;                // [B, T, E] fp32

  // ws layout
  bf16* xbT = (bf16*)d_ws;                        // [B][C][T]  8.4 MB
  bf16* wbT = xbT + (size_t)B_ * C_ * T_;         // [E][D]    33.5 MB
  bf16* xh = wbT + (size_t)E_ * D_;               // [B][H][T][64] 8.4 MB
  bf16* Obuf = xh + (size_t)B_ * H_ * T_ * 64;    // [B*T][D]  134 MB
  float* lsum = (float*)(Obuf + (size_t)B_ * T_ * D_);  // [B*H][T] 256 KB
  bf16* P = (bf16*)(lsum + (size_t)B_ * H_ * T_);  // [Hs][T][T] slab
  float* partials = (float*)P;                     // proj partials (67 MB)

  size_t fixed = ((size_t)B_ * C_ * T_ + (size_t)E_ * D_ +
                  (size_t)B_ * H_ * T_ * 64 + (size_t)B_ * T_ * D_) * 2 +
                 (size_t)B_ * H_ * T_ * 4;
  // head-slab size so the P slab fits in the remaining workspace
  int Hs = 16;
  while (Hs > 1 && fixed + (size_t)Hs * T_ * T_ * 2 > ws_size) Hs >>= 1;
  bool bigP = fixed + (size_t)32 * T_ * T_ * 2 <= ws_size;  // both batches

  xprep_kernel<<<dim3(C_ / 32, T_ / 32, B_), dim3(32, 8), 0, stream>>>(x, xbT,
                                                                       xh);
  transpose_cast_kernel<<<dim3(E_ / 32, D_ / 32, 1), dim3(32, 8), 0, stream>>>(
      wgt, wbT, D_, E_);
  hipMemsetAsync(lsum, 0, (size_t)B_ * H_ * T_ * sizeof(float), stream);

  if (bigP) {
    // both batches in one scores dispatch + one PV dispatch (z = b*16+h)
    scores_kernel<<<dim3(136, 32), 256, 0, stream>>>(xh, P, lsum);
    gemm_bt_kernel<3, 1><<<dim3(C_ / 128, T_ / 128, 32), 256, 0, stream>>>(
        P, 16LL * T_ * T_, (long long)T_ * T_, T_,
        xbT, (long long)C_ * T_, 0LL, T_,
        (void*)Obuf, D_, (long long)T_ * D_, (long long)C_, lsum, T_);
  } else {
    for (int b = 0; b < B_; ++b) {
      for (int h0 = 0; h0 < H_; h0 += Hs) {
        const bf16* xhs = xh + (size_t)(b * H_ + h0) * T_ * 64;
        float* lsl = lsum + (size_t)(b * H_ + h0) * T_;
        scores_kernel<<<dim3(136, Hs), 256, 0, stream>>>(xhs, P, lsl);
        gemm_bt_kernel<3, 1><<<dim3(C_ / 128, T_ / 128, Hs), 256, 0, stream>>>(
            P, 0LL, (long long)T_ * T_, T_,
            xbT + (size_t)b * C_ * T_, 0LL, 0LL, T_,
            (void*)(Obuf + (size_t)b * T_ * D_ + (size_t)h0 * C_), D_, 0LL,
            (long long)C_, lsl, T_);
      }
    }
  }
  // proj: partials[z] = O[:, z*4096:(z+1)*4096] @ W[z*4096:(z+1)*4096, :]
  gemm_bt_kernel<0, 1><<<dim3(E_ / 128, (B_ * T_) / 128, KZ_), 256, 0,
                         stream>>>(Obuf, 0LL, (long long)(D_ / KZ_), D_,
                                   wbT, 0LL, (long long)(D_ / KZ_), D_,
                                   (void*)partials, E_, 0LL,
                                   (long long)B_ * T_ * E_, nullptr, D_ / KZ_);
  reduce_kernel<<<(B_ * T_ * E_ / 4 + 255) / 256, 256, 0, stream>>>(
      partials, out, B_ * T_ * E_ / 4);
}